// Round 1
// baseline (484.924 us; speedup 1.0000x reference)
//
#include <hip/hip_runtime.h>

#define WS_ALIGN(x) (((x) + size_t(255)) & ~size_t(255))

__global__ __launch_bounds__(256) void k_zero(int* p, int n) {
    int i = blockIdx.x * 256 + threadIdx.x;
    if (i < n) p[i] = 0;
}

__global__ __launch_bounds__(256) void k_count(const int* col, int* deg, int E) {
    int e = blockIdx.x * 256 + threadIdx.x;
    if (e < E) atomicAdd(&deg[col[e]], 1);
}

// per-block inclusive scan of deg -> offs1 (= offsets+1), block totals -> bsums
__global__ __launch_bounds__(1024) void k_scan_blocks(const int* deg, int* offs1, int* bsums, int n) {
    __shared__ int s[1024];
    int gid = blockIdx.x * 1024 + threadIdx.x;
    int v = (gid < n) ? deg[gid] : 0;
    s[threadIdx.x] = v;
    __syncthreads();
    for (int d = 1; d < 1024; d <<= 1) {
        int t = (threadIdx.x >= (unsigned)d) ? s[threadIdx.x - d] : 0;
        __syncthreads();
        s[threadIdx.x] += t;
        __syncthreads();
    }
    if (gid < n) offs1[gid] = s[threadIdx.x];
    if (threadIdx.x == 1023) bsums[blockIdx.x] = s[1023];
}

// single-block scan of block sums -> exclusive
__global__ __launch_bounds__(1024) void k_scan_sums(int* bsums, int nb) {
    __shared__ int s[1024];
    int v = (threadIdx.x < (unsigned)nb) ? bsums[threadIdx.x] : 0;
    s[threadIdx.x] = v;
    __syncthreads();
    for (int d = 1; d < 1024; d <<= 1) {
        int t = (threadIdx.x >= (unsigned)d) ? s[threadIdx.x - d] : 0;
        __syncthreads();
        s[threadIdx.x] += t;
        __syncthreads();
    }
    if (threadIdx.x < (unsigned)nb) bsums[threadIdx.x] = s[threadIdx.x] - v; // exclusive
}

__global__ __launch_bounds__(256) void k_add_offsets(int* offs, const int* bsums, int n) {
    int gid = blockIdx.x * 256 + threadIdx.x;
    if (gid < n) offs[gid + 1] += bsums[gid >> 10];
    if (gid == 0) offs[0] = 0;
}

__global__ __launch_bounds__(256) void k_dinv_cursor(const int* deg, const int* offs,
                                                     float* dinv, int* cursor, int n) {
    int i = blockIdx.x * 256 + threadIdx.x;
    if (i >= n) return;
    dinv[i] = rsqrtf((float)(deg[i] + 1));  // +1 self loop; deg>0 always
    cursor[i] = offs[i];
}

__global__ __launch_bounds__(256) void k_bin(const int* row, const int* col,
                                             int* cursor, int* adj, int E) {
    int e = blockIdx.x * 256 + threadIdx.x;
    if (e >= E) return;
    int c = col[e];
    int p = atomicAdd(&cursor[c], 1);
    adj[p] = row[e];
}

// h1 = x @ W1   (x: [n,128], W1: [128,64]) — one wave per node, lane = out channel
__global__ __launch_bounds__(256) void k_gemm1(const float* __restrict__ x,
                                               const float* __restrict__ W1,
                                               float* __restrict__ h1, int n) {
    __shared__ float Wl[128 * 64];
    __shared__ float xs[4][128];
    for (int t = threadIdx.x; t < 2048; t += 256)
        ((float4*)Wl)[t] = ((const float4*)W1)[t];
    int base = blockIdx.x * 4;
    for (int t = threadIdx.x; t < 512; t += 256) {
        int r = t >> 7, k = t & 127;
        int nd = base + r;
        xs[r][k] = (nd < n) ? x[(size_t)nd * 128 + k] : 0.f;
    }
    __syncthreads();
    int wid = threadIdx.x >> 6, lane = threadIdx.x & 63;
    int node = base + wid;
    if (node < n) {
        float acc = 0.f;
#pragma unroll
        for (int k = 0; k < 128; k++)
            acc = fmaf(xs[wid][k], Wl[k * 64 + lane], acc);
        h1[(size_t)node * 64 + lane] = acc;
    }
}

// layer-1 aggregation: wave per node, lane = channel; + b1 + relu
__global__ __launch_bounds__(256) void k_agg1(const float* __restrict__ h1,
                                              const float* __restrict__ dinv,
                                              const int* __restrict__ offs,
                                              const int* __restrict__ adj,
                                              const float* __restrict__ b1,
                                              float* __restrict__ hmid, int n) {
    int wid = threadIdx.x >> 6, lane = threadIdx.x & 63;
    int i = blockIdx.x * 4 + wid;
    if (i >= n) return;
    int s = offs[i], e = offs[i + 1];
    float acc = 0.f;
    for (int p = s; p < e; p++) {
        int src = adj[p];
        acc = fmaf(h1[(size_t)src * 64 + lane], dinv[src], acc);
    }
    float di = dinv[i];
    float val = fmaf(acc, di, h1[(size_t)i * 64 + lane] * di * di) + b1[lane];
    hmid[(size_t)i * 64 + lane] = fmaxf(val, 0.f);
}

// h2 = hmid @ W2  (W2: [64,2]); thread per node
__global__ __launch_bounds__(256) void k_gemm2(const float* __restrict__ hmid,
                                               const float* __restrict__ W2,
                                               float* __restrict__ h2, int n) {
    __shared__ float Ws[128];
    if (threadIdx.x < 128) Ws[threadIdx.x] = W2[threadIdx.x];
    __syncthreads();
    int i = blockIdx.x * 256 + threadIdx.x;
    if (i >= n) return;
    float a0 = 0.f, a1 = 0.f;
    const float4* r = (const float4*)(hmid + (size_t)i * 64);
#pragma unroll
    for (int k = 0; k < 16; k++) {
        float4 v = r[k];
        a0 = fmaf(v.x, Ws[(4 * k + 0) * 2], a0);
        a1 = fmaf(v.x, Ws[(4 * k + 0) * 2 + 1], a1);
        a0 = fmaf(v.y, Ws[(4 * k + 1) * 2], a0);
        a1 = fmaf(v.y, Ws[(4 * k + 1) * 2 + 1], a1);
        a0 = fmaf(v.z, Ws[(4 * k + 2) * 2], a0);
        a1 = fmaf(v.z, Ws[(4 * k + 2) * 2 + 1], a1);
        a0 = fmaf(v.w, Ws[(4 * k + 3) * 2], a0);
        a1 = fmaf(v.w, Ws[(4 * k + 3) * 2 + 1], a1);
    }
    h2[(size_t)i * 2] = a0;
    h2[(size_t)i * 2 + 1] = a1;
}

// layer-2 aggregation: thread per node (2 channels); + b2; write final output
__global__ __launch_bounds__(256) void k_agg2(const float* __restrict__ h2,
                                              const float* __restrict__ dinv,
                                              const int* __restrict__ offs,
                                              const int* __restrict__ adj,
                                              const float* __restrict__ b2,
                                              float* __restrict__ out, int n) {
    int i = blockIdx.x * 256 + threadIdx.x;
    if (i >= n) return;
    int s = offs[i], e = offs[i + 1];
    float a0 = 0.f, a1 = 0.f;
    for (int p = s; p < e; p++) {
        int src = adj[p];
        float d = dinv[src];
        float2 v = *(const float2*)(h2 + (size_t)src * 2);
        a0 = fmaf(v.x, d, a0);
        a1 = fmaf(v.y, d, a1);
    }
    float di = dinv[i];
    float2 hv = *(const float2*)(h2 + (size_t)i * 2);
    out[(size_t)i * 2]     = fmaf(a0, di, hv.x * di * di) + b2[0];
    out[(size_t)i * 2 + 1] = fmaf(a1, di, hv.y * di * di) + b2[1];
}

extern "C" void kernel_launch(void* const* d_in, const int* in_sizes, int n_in,
                              void* d_out, int out_size, void* d_ws, size_t ws_size,
                              hipStream_t stream) {
    const float* x  = (const float*)d_in[0];
    const int*   ei = (const int*)d_in[1];
    const float* W1 = (const float*)d_in[2];
    const float* b1 = (const float*)d_in[3];
    const float* W2 = (const float*)d_in[4];
    const float* b2 = (const float*)d_in[5];
    float* out = (float*)d_out;

    int N = in_sizes[0] / 128;   // 100000
    int E = in_sizes[1] / 2;     // 1600000
    const int* row = ei;
    const int* col = ei + E;

    char* ws = (char*)d_ws;
    size_t off = 0;
    auto alloc = [&](size_t bytes) -> char* {
        char* p = ws + off;
        off = WS_ALIGN(off + bytes);
        return p;
    };
    int*   deg    = (int*)alloc((size_t)N * 4);
    int*   offs   = (int*)alloc((size_t)(N + 1) * 4);
    int*   cursor = (int*)alloc((size_t)N * 4);
    int*   bsums  = (int*)alloc(4096);
    float* dinv   = (float*)alloc((size_t)N * 4);
    int*   adj    = (int*)alloc((size_t)E * 4);
    float* h1     = (float*)alloc((size_t)N * 64 * 4);
    float* hmid   = (float*)alloc((size_t)N * 64 * 4);
    float* h2     = (float*)alloc((size_t)N * 2 * 4);

    int nb = (N + 1023) / 1024;

    hipLaunchKernelGGL(k_zero, dim3((N + 255) / 256), dim3(256), 0, stream, deg, N);
    hipLaunchKernelGGL(k_count, dim3((E + 255) / 256), dim3(256), 0, stream, col, deg, E);
    hipLaunchKernelGGL(k_scan_blocks, dim3(nb), dim3(1024), 0, stream, deg, offs + 1, bsums, N);
    hipLaunchKernelGGL(k_scan_sums, dim3(1), dim3(1024), 0, stream, bsums, nb);
    hipLaunchKernelGGL(k_add_offsets, dim3((N + 255) / 256), dim3(256), 0, stream, offs, bsums, N);
    hipLaunchKernelGGL(k_dinv_cursor, dim3((N + 255) / 256), dim3(256), 0, stream, deg, offs, dinv, cursor, N);
    hipLaunchKernelGGL(k_bin, dim3((E + 255) / 256), dim3(256), 0, stream, row, col, cursor, adj, E);
    hipLaunchKernelGGL(k_gemm1, dim3((N + 3) / 4), dim3(256), 0, stream, x, W1, h1, N);
    hipLaunchKernelGGL(k_agg1, dim3((N + 3) / 4), dim3(256), 0, stream, h1, dinv, offs, adj, b1, hmid, N);
    hipLaunchKernelGGL(k_gemm2, dim3((N + 255) / 256), dim3(256), 0, stream, hmid, W2, h2, N);
    hipLaunchKernelGGL(k_agg2, dim3((N + 255) / 256), dim3(256), 0, stream, h2, dinv, offs, adj, b2, out, N);
}

// Round 2
// 316.307 us; speedup vs baseline: 1.5331x; 1.5331x over previous
//
#include <hip/hip_runtime.h>

#define WS_ALIGN(x) (((x) + size_t(255)) & ~size_t(255))

__global__ __launch_bounds__(256) void k_count(const int* __restrict__ col, int* deg, int E) {
    int e = blockIdx.x * 256 + threadIdx.x;
    if (e < E) atomicAdd(&deg[col[e]], 1);
}

// per-block inclusive scan of deg -> offs1 (= offsets+1), block totals -> bsums
__global__ __launch_bounds__(1024) void k_scan_blocks(const int* deg, int* offs1, int* bsums, int n) {
    __shared__ int s[1024];
    int gid = blockIdx.x * 1024 + threadIdx.x;
    int v = (gid < n) ? deg[gid] : 0;
    s[threadIdx.x] = v;
    __syncthreads();
    for (int d = 1; d < 1024; d <<= 1) {
        int t = (threadIdx.x >= (unsigned)d) ? s[threadIdx.x - d] : 0;
        __syncthreads();
        s[threadIdx.x] += t;
        __syncthreads();
    }
    if (gid < n) offs1[gid] = s[threadIdx.x];
    if (threadIdx.x == 1023) bsums[blockIdx.x] = s[1023];
}

__global__ __launch_bounds__(1024) void k_scan_sums(int* bsums, int nb) {
    __shared__ int s[1024];
    int v = (threadIdx.x < (unsigned)nb) ? bsums[threadIdx.x] : 0;
    s[threadIdx.x] = v;
    __syncthreads();
    for (int d = 1; d < 1024; d <<= 1) {
        int t = (threadIdx.x >= (unsigned)d) ? s[threadIdx.x - d] : 0;
        __syncthreads();
        s[threadIdx.x] += t;
        __syncthreads();
    }
    if (threadIdx.x < (unsigned)nb) bsums[threadIdx.x] = s[threadIdx.x] - v; // exclusive
}

__global__ __launch_bounds__(256) void k_add_offsets(int* offs, const int* bsums, int n) {
    int gid = blockIdx.x * 256 + threadIdx.x;
    if (gid < n) offs[gid + 1] += bsums[gid >> 10];
    if (gid == 0) offs[0] = 0;
}

__global__ __launch_bounds__(256) void k_dinv_cursor(const int* deg, const int* offs,
                                                     float* dinv, int* cursor, int n) {
    int i = blockIdx.x * 256 + threadIdx.x;
    if (i >= n) return;
    dinv[i] = rsqrtf((float)(deg[i] + 1));  // +1 self loop
    cursor[i] = offs[i];
}

__global__ __launch_bounds__(256) void k_bin(const int* __restrict__ row, const int* __restrict__ col,
                                             int* cursor, int* adj, int E) {
    int e = blockIdx.x * 256 + threadIdx.x;
    if (e >= E) return;
    int c = col[e];
    int p = atomicAdd(&cursor[c], 1);
    adj[p] = row[e];
}

// h1s = (x @ W1) * dinv[node]   x:[n,128] W1:[128,64]
// 32 nodes/block, 4 waves, 8 nodes/wave; lane: r=lane&7 (node), cg=lane>>3 (8 channels)
__global__ __launch_bounds__(256) void k_gemm1(const float* __restrict__ x,
                                               const float* __restrict__ W1,
                                               const float* __restrict__ dinv,
                                               float* __restrict__ h1s, int n) {
    __shared__ float xs[32][132];   // padded: bank = (4*node + k) % 32 -> conflict-free
    __shared__ float Ws[128][64];
    int base = blockIdx.x * 32;
    // stage x (32 nodes x 128), float4
    for (int q = threadIdx.x; q < 1024; q += 256) {
        int nd = q >> 5, kf = q & 31;
        int gn = base + nd;
        float4 v = (gn < n) ? *(const float4*)&x[(size_t)gn * 128 + kf * 4]
                            : make_float4(0.f, 0.f, 0.f, 0.f);
        *(float4*)&xs[nd][kf * 4] = v;
    }
    // stage W1 (128x64), float4
    for (int q = threadIdx.x; q < 2048; q += 256) {
        float4 v = ((const float4*)W1)[q];
        int k = q >> 4, cf = q & 15;
        *(float4*)&Ws[k][cf * 4] = v;
    }
    __syncthreads();

    int wid = threadIdx.x >> 6, lane = threadIdx.x & 63;
    int r = (wid << 3) + (lane & 7);      // node within block (0..31)
    int cbase = (lane >> 3) << 3;         // channel base (0..56 step 8)
    float4 a0 = make_float4(0.f, 0.f, 0.f, 0.f);
    float4 a1 = make_float4(0.f, 0.f, 0.f, 0.f);
#pragma unroll 4
    for (int k4 = 0; k4 < 32; k4++) {
        float4 xv = *(const float4*)&xs[r][k4 * 4];
#pragma unroll
        for (int kk = 0; kk < 4; kk++) {
            float xk = (&xv.x)[kk];
            float4 w0 = *(const float4*)&Ws[k4 * 4 + kk][cbase];
            float4 w1 = *(const float4*)&Ws[k4 * 4 + kk][cbase + 4];
            a0.x = fmaf(xk, w0.x, a0.x); a0.y = fmaf(xk, w0.y, a0.y);
            a0.z = fmaf(xk, w0.z, a0.z); a0.w = fmaf(xk, w0.w, a0.w);
            a1.x = fmaf(xk, w1.x, a1.x); a1.y = fmaf(xk, w1.y, a1.y);
            a1.z = fmaf(xk, w1.z, a1.z); a1.w = fmaf(xk, w1.w, a1.w);
        }
    }
    int node = base + r;
    if (node < n) {
        float di = dinv[node];
        a0.x *= di; a0.y *= di; a0.z *= di; a0.w *= di;
        a1.x *= di; a1.y *= di; a1.z *= di; a1.w *= di;
        float* o = &h1s[(size_t)node * 64 + cbase];
        *(float4*)o = a0;
        *(float4*)(o + 4) = a1;
    }
}

// layer-1 aggregation fused with layer-2 GEMM:
// wave per node, lane = channel; hmid = relu(di*(sum h1s[src] + h1s[i]) + b1)
// then h2s[i] = (hmid @ W2) * di  via 64-lane shuffle reduction
__global__ __launch_bounds__(256) void k_agg1(const float* __restrict__ h1s,
                                              const float* __restrict__ dinv,
                                              const int* __restrict__ offs,
                                              const int* __restrict__ adj,
                                              const float* __restrict__ b1,
                                              const float* __restrict__ W2,
                                              float* __restrict__ h2s, int n) {
    int wid = threadIdx.x >> 6, lane = threadIdx.x & 63;
    int i = blockIdx.x * 4 + wid;
    if (i >= n) return;
    int s = __builtin_amdgcn_readfirstlane(offs[i]);
    int e = __builtin_amdgcn_readfirstlane(offs[i + 1]);
    float acc0 = 0.f, acc1 = 0.f, acc2 = 0.f, acc3 = 0.f;
    int p = s;
    for (; p + 4 <= e; p += 4) {
        int s0 = adj[p], s1 = adj[p + 1], s2 = adj[p + 2], s3 = adj[p + 3];
        acc0 += h1s[(size_t)s0 * 64 + lane];
        acc1 += h1s[(size_t)s1 * 64 + lane];
        acc2 += h1s[(size_t)s2 * 64 + lane];
        acc3 += h1s[(size_t)s3 * 64 + lane];
    }
    int rem = e - p;
    if (rem > 0) {
        int q0 = adj[p];
        int q1 = (rem > 1) ? adj[p + 1] : q0;
        int q2 = (rem > 2) ? adj[p + 2] : q0;
        float v0 = h1s[(size_t)q0 * 64 + lane];
        float v1 = h1s[(size_t)q1 * 64 + lane];
        float v2 = h1s[(size_t)q2 * 64 + lane];
        acc0 += v0;
        if (rem > 1) acc1 += v1;
        if (rem > 2) acc2 += v2;
    }
    float acc = (acc0 + acc1) + (acc2 + acc3);
    float di = dinv[i];
    float val = fmaf(di, acc + h1s[(size_t)i * 64 + lane], b1[lane]);
    val = fmaxf(val, 0.f);  // hmid channel `lane` of node i, in register
    // fused layer-2 GEMM: h2[i][j] = sum_c hmid[c] * W2[c][j]
    float w0 = W2[lane * 2], w1 = W2[lane * 2 + 1];
    float t0 = val * w0, t1 = val * w1;
#pragma unroll
    for (int m = 1; m < 64; m <<= 1) {
        t0 += __shfl_xor(t0, m, 64);
        t1 += __shfl_xor(t1, m, 64);
    }
    if (lane == 0) {
        h2s[(size_t)i * 2]     = t0 * di;
        h2s[(size_t)i * 2 + 1] = t1 * di;
    }
}

// layer-2 aggregation: thread per node; out = di*(sum h2s[src] + h2s[i]) + b2
__global__ __launch_bounds__(256) void k_agg2(const float* __restrict__ h2s,
                                              const float* __restrict__ dinv,
                                              const int* __restrict__ offs,
                                              const int* __restrict__ adj,
                                              const float* __restrict__ b2,
                                              float* __restrict__ out, int n) {
    int i = blockIdx.x * 256 + threadIdx.x;
    if (i >= n) return;
    int s = offs[i], e = offs[i + 1];
    float a0x = 0.f, a0y = 0.f, a1x = 0.f, a1y = 0.f;
    float a2x = 0.f, a2y = 0.f, a3x = 0.f, a3y = 0.f;
    int p = s;
    for (; p + 4 <= e; p += 4) {
        int s0 = adj[p], s1 = adj[p + 1], s2 = adj[p + 2], s3 = adj[p + 3];
        float2 v0 = *(const float2*)(h2s + (size_t)s0 * 2);
        float2 v1 = *(const float2*)(h2s + (size_t)s1 * 2);
        float2 v2 = *(const float2*)(h2s + (size_t)s2 * 2);
        float2 v3 = *(const float2*)(h2s + (size_t)s3 * 2);
        a0x += v0.x; a0y += v0.y;
        a1x += v1.x; a1y += v1.y;
        a2x += v2.x; a2y += v2.y;
        a3x += v3.x; a3y += v3.y;
    }
    int rem = e - p;
    if (rem > 0) {
        int q0 = adj[p];
        int q1 = (rem > 1) ? adj[p + 1] : q0;
        int q2 = (rem > 2) ? adj[p + 2] : q0;
        float2 v0 = *(const float2*)(h2s + (size_t)q0 * 2);
        float2 v1 = *(const float2*)(h2s + (size_t)q1 * 2);
        float2 v2 = *(const float2*)(h2s + (size_t)q2 * 2);
        a0x += v0.x; a0y += v0.y;
        if (rem > 1) { a1x += v1.x; a1y += v1.y; }
        if (rem > 2) { a2x += v2.x; a2y += v2.y; }
    }
    float ax = (a0x + a1x) + (a2x + a3x);
    float ay = (a0y + a1y) + (a2y + a3y);
    float di = dinv[i];
    float2 hv = *(const float2*)(h2s + (size_t)i * 2);
    out[(size_t)i * 2]     = fmaf(di, ax + hv.x, b2[0]);
    out[(size_t)i * 2 + 1] = fmaf(di, ay + hv.y, b2[1]);
}

extern "C" void kernel_launch(void* const* d_in, const int* in_sizes, int n_in,
                              void* d_out, int out_size, void* d_ws, size_t ws_size,
                              hipStream_t stream) {
    const float* x  = (const float*)d_in[0];
    const int*   ei = (const int*)d_in[1];
    const float* W1 = (const float*)d_in[2];
    const float* b1 = (const float*)d_in[3];
    const float* W2 = (const float*)d_in[4];
    const float* b2 = (const float*)d_in[5];
    float* out = (float*)d_out;

    int N = in_sizes[0] / 128;   // 100000
    int E = in_sizes[1] / 2;     // 1600000
    const int* row = ei;
    const int* col = ei + E;

    char* ws = (char*)d_ws;
    size_t off = 0;
    auto alloc = [&](size_t bytes) -> char* {
        char* p = ws + off;
        off = WS_ALIGN(off + bytes);
        return p;
    };
    int*   deg    = (int*)alloc((size_t)N * 4);
    int*   offs   = (int*)alloc((size_t)(N + 1) * 4);
    int*   cursor = (int*)alloc((size_t)N * 4);
    int*   bsums  = (int*)alloc(4096);
    float* dinv   = (float*)alloc((size_t)N * 4);
    int*   adj    = (int*)alloc((size_t)E * 4);
    float* h1s    = (float*)alloc((size_t)N * 64 * 4);
    float* h2s    = (float*)alloc((size_t)N * 2 * 4);

    int nb = (N + 1023) / 1024;

    hipMemsetAsync(deg, 0, (size_t)N * 4, stream);
    hipLaunchKernelGGL(k_count, dim3((E + 255) / 256), dim3(256), 0, stream, col, deg, E);
    hipLaunchKernelGGL(k_scan_blocks, dim3(nb), dim3(1024), 0, stream, deg, offs + 1, bsums, N);
    hipLaunchKernelGGL(k_scan_sums, dim3(1), dim3(1024), 0, stream, bsums, nb);
    hipLaunchKernelGGL(k_add_offsets, dim3((N + 255) / 256), dim3(256), 0, stream, offs, bsums, N);
    hipLaunchKernelGGL(k_dinv_cursor, dim3((N + 255) / 256), dim3(256), 0, stream, deg, offs, dinv, cursor, N);
    hipLaunchKernelGGL(k_bin, dim3((E + 255) / 256), dim3(256), 0, stream, row, col, cursor, adj, E);
    hipLaunchKernelGGL(k_gemm1, dim3((N + 31) / 32), dim3(256), 0, stream, x, W1, dinv, h1s, N);
    hipLaunchKernelGGL(k_agg1, dim3((N + 3) / 4), dim3(256), 0, stream, h1s, dinv, offs, adj, b1, W2, h2s, N);
    hipLaunchKernelGGL(k_agg2, dim3((N + 255) / 256), dim3(256), 0, stream, h2s, dinv, offs, adj, b2, out, N);
}

// Round 3
// 264.635 us; speedup vs baseline: 1.8324x; 1.1953x over previous
//
#include <hip/hip_runtime.h>

#define WS_ALIGN(x) (((x) + size_t(255)) & ~size_t(255))

__global__ __launch_bounds__(256) void k_count(const int* __restrict__ col, int* deg, int E) {
    int e = blockIdx.x * 256 + threadIdx.x;
    if (e < E) atomicAdd(&deg[col[e]], 1);
}

// per-block inclusive scan of deg -> offs1 (= offsets+1), block totals -> bsums
__global__ __launch_bounds__(1024) void k_scan_blocks(const int* deg, int* offs1, int* bsums, int n) {
    __shared__ int s[1024];
    int gid = blockIdx.x * 1024 + threadIdx.x;
    int v = (gid < n) ? deg[gid] : 0;
    s[threadIdx.x] = v;
    __syncthreads();
    for (int d = 1; d < 1024; d <<= 1) {
        int t = (threadIdx.x >= (unsigned)d) ? s[threadIdx.x - d] : 0;
        __syncthreads();
        s[threadIdx.x] += t;
        __syncthreads();
    }
    if (gid < n) offs1[gid] = s[threadIdx.x];
    if (threadIdx.x == 1023) bsums[blockIdx.x] = s[1023];
}

__global__ __launch_bounds__(1024) void k_scan_sums(int* bsums, int nb) {
    __shared__ int s[1024];
    int v = (threadIdx.x < (unsigned)nb) ? bsums[threadIdx.x] : 0;
    s[threadIdx.x] = v;
    __syncthreads();
    for (int d = 1; d < 1024; d <<= 1) {
        int t = (threadIdx.x >= (unsigned)d) ? s[threadIdx.x - d] : 0;
        __syncthreads();
        s[threadIdx.x] += t;
        __syncthreads();
    }
    if (threadIdx.x < (unsigned)nb) bsums[threadIdx.x] = s[threadIdx.x] - v; // exclusive
}

__global__ __launch_bounds__(256) void k_add_offsets(int* offs, const int* bsums, int n) {
    int gid = blockIdx.x * 256 + threadIdx.x;
    if (gid < n) offs[gid + 1] += bsums[gid >> 10];
    if (gid == 0) offs[0] = 0;
}

__global__ __launch_bounds__(256) void k_dinv_cursor(const int* deg, const int* offs,
                                                     float* dinv, int* cursor, int n) {
    int i = blockIdx.x * 256 + threadIdx.x;
    if (i >= n) return;
    dinv[i] = rsqrtf((float)(deg[i] + 1));  // +1 self loop
    cursor[i] = offs[i];
}

// XCD-partitioned binning: group g = blockIdx&7 owns cols [g*npg, (g+1)*npg).
// With round-robin blockIdx->XCD mapping, each adj slice is written by one XCD
// only -> dirty lines stay in that L2, writebacks drop ~16x. Correct under ANY
// mapping (each edge binned exactly once by the group owning its col).
__global__ __launch_bounds__(256) void k_bin(const int* __restrict__ row,
                                             const int* __restrict__ col,
                                             int* cursor, int* adj, int E, int npg) {
    int g = blockIdx.x & 7;
    int j = blockIdx.x >> 3;
    int nblk = gridDim.x >> 3;
    int lo = g * npg, hi = lo + npg;
    for (int e = j * 256 + threadIdx.x; e < E; e += nblk * 256) {
        int c = col[e];
        if (c >= lo && c < hi) {
            int p = atomicAdd(&cursor[c], 1);
            adj[p] = row[e];
        }
    }
}

// h1s = (x @ W1) * dinv[node]   x:[n,128] W1:[128,64]
__global__ __launch_bounds__(256) void k_gemm1(const float* __restrict__ x,
                                               const float* __restrict__ W1,
                                               const float* __restrict__ dinv,
                                               float* __restrict__ h1s, int n) {
    __shared__ float xs[32][132];
    __shared__ float Ws[128][64];
    int base = blockIdx.x * 32;
    for (int q = threadIdx.x; q < 1024; q += 256) {
        int nd = q >> 5, kf = q & 31;
        int gn = base + nd;
        float4 v = (gn < n) ? *(const float4*)&x[(size_t)gn * 128 + kf * 4]
                            : make_float4(0.f, 0.f, 0.f, 0.f);
        *(float4*)&xs[nd][kf * 4] = v;
    }
    for (int q = threadIdx.x; q < 2048; q += 256) {
        float4 v = ((const float4*)W1)[q];
        int k = q >> 4, cf = q & 15;
        *(float4*)&Ws[k][cf * 4] = v;
    }
    __syncthreads();

    int wid = threadIdx.x >> 6, lane = threadIdx.x & 63;
    int r = (wid << 3) + (lane & 7);
    int cbase = (lane >> 3) << 3;
    float4 a0 = make_float4(0.f, 0.f, 0.f, 0.f);
    float4 a1 = make_float4(0.f, 0.f, 0.f, 0.f);
#pragma unroll 4
    for (int k4 = 0; k4 < 32; k4++) {
        float4 xv = *(const float4*)&xs[r][k4 * 4];
#pragma unroll
        for (int kk = 0; kk < 4; kk++) {
            float xk = (&xv.x)[kk];
            float4 w0 = *(const float4*)&Ws[k4 * 4 + kk][cbase];
            float4 w1 = *(const float4*)&Ws[k4 * 4 + kk][cbase + 4];
            a0.x = fmaf(xk, w0.x, a0.x); a0.y = fmaf(xk, w0.y, a0.y);
            a0.z = fmaf(xk, w0.z, a0.z); a0.w = fmaf(xk, w0.w, a0.w);
            a1.x = fmaf(xk, w1.x, a1.x); a1.y = fmaf(xk, w1.y, a1.y);
            a1.z = fmaf(xk, w1.z, a1.z); a1.w = fmaf(xk, w1.w, a1.w);
        }
    }
    int node = base + r;
    if (node < n) {
        float di = dinv[node];
        a0.x *= di; a0.y *= di; a0.z *= di; a0.w *= di;
        a1.x *= di; a1.y *= di; a1.z *= di; a1.w *= di;
        float* o = &h1s[(size_t)node * 64 + cbase];
        *(float4*)o = a0;
        *(float4*)(o + 4) = a1;
    }
}

// layer-1 aggregation fused with layer-2 GEMM (shuffle reduction)
__global__ __launch_bounds__(256) void k_agg1(const float* __restrict__ h1s,
                                              const float* __restrict__ dinv,
                                              const int* __restrict__ offs,
                                              const int* __restrict__ adj,
                                              const float* __restrict__ b1,
                                              const float* __restrict__ W2,
                                              float* __restrict__ h2s, int n) {
    int wid = threadIdx.x >> 6, lane = threadIdx.x & 63;
    int i = blockIdx.x * 4 + wid;
    if (i >= n) return;
    int s = __builtin_amdgcn_readfirstlane(offs[i]);
    int e = __builtin_amdgcn_readfirstlane(offs[i + 1]);
    float acc0 = 0.f, acc1 = 0.f, acc2 = 0.f, acc3 = 0.f;
    int p = s;
    for (; p + 4 <= e; p += 4) {
        int s0 = adj[p], s1 = adj[p + 1], s2 = adj[p + 2], s3 = adj[p + 3];
        acc0 += h1s[(size_t)s0 * 64 + lane];
        acc1 += h1s[(size_t)s1 * 64 + lane];
        acc2 += h1s[(size_t)s2 * 64 + lane];
        acc3 += h1s[(size_t)s3 * 64 + lane];
    }
    int rem = e - p;
    if (rem > 0) {
        int q0 = adj[p];
        int q1 = (rem > 1) ? adj[p + 1] : q0;
        int q2 = (rem > 2) ? adj[p + 2] : q0;
        float v0 = h1s[(size_t)q0 * 64 + lane];
        float v1 = h1s[(size_t)q1 * 64 + lane];
        float v2 = h1s[(size_t)q2 * 64 + lane];
        acc0 += v0;
        if (rem > 1) acc1 += v1;
        if (rem > 2) acc2 += v2;
    }
    float acc = (acc0 + acc1) + (acc2 + acc3);
    float di = dinv[i];
    float val = fmaf(di, acc + h1s[(size_t)i * 64 + lane], b1[lane]);
    val = fmaxf(val, 0.f);
    float w0 = W2[lane * 2], w1 = W2[lane * 2 + 1];
    float t0 = val * w0, t1 = val * w1;
#pragma unroll
    for (int m = 1; m < 64; m <<= 1) {
        t0 += __shfl_xor(t0, m, 64);
        t1 += __shfl_xor(t1, m, 64);
    }
    if (lane == 0) {
        h2s[(size_t)i * 2]     = t0 * di;
        h2s[(size_t)i * 2 + 1] = t1 * di;
    }
}

// layer-2 aggregation: thread per node; out = di*(sum h2s[src] + h2s[i]) + b2
__global__ __launch_bounds__(256) void k_agg2(const float* __restrict__ h2s,
                                              const float* __restrict__ dinv,
                                              const int* __restrict__ offs,
                                              const int* __restrict__ adj,
                                              const float* __restrict__ b2,
                                              float* __restrict__ out, int n) {
    int i = blockIdx.x * 256 + threadIdx.x;
    if (i >= n) return;
    int s = offs[i], e = offs[i + 1];
    float a0x = 0.f, a0y = 0.f, a1x = 0.f, a1y = 0.f;
    float a2x = 0.f, a2y = 0.f, a3x = 0.f, a3y = 0.f;
    int p = s;
    for (; p + 4 <= e; p += 4) {
        int s0 = adj[p], s1 = adj[p + 1], s2 = adj[p + 2], s3 = adj[p + 3];
        float2 v0 = *(const float2*)(h2s + (size_t)s0 * 2);
        float2 v1 = *(const float2*)(h2s + (size_t)s1 * 2);
        float2 v2 = *(const float2*)(h2s + (size_t)s2 * 2);
        float2 v3 = *(const float2*)(h2s + (size_t)s3 * 2);
        a0x += v0.x; a0y += v0.y;
        a1x += v1.x; a1y += v1.y;
        a2x += v2.x; a2y += v2.y;
        a3x += v3.x; a3y += v3.y;
    }
    int rem = e - p;
    if (rem > 0) {
        int q0 = adj[p];
        int q1 = (rem > 1) ? adj[p + 1] : q0;
        int q2 = (rem > 2) ? adj[p + 2] : q0;
        float2 v0 = *(const float2*)(h2s + (size_t)q0 * 2);
        float2 v1 = *(const float2*)(h2s + (size_t)q1 * 2);
        float2 v2 = *(const float2*)(h2s + (size_t)q2 * 2);
        a0x += v0.x; a0y += v0.y;
        if (rem > 1) { a1x += v1.x; a1y += v1.y; }
        if (rem > 2) { a2x += v2.x; a2y += v2.y; }
    }
    float ax = (a0x + a1x) + (a2x + a3x);
    float ay = (a0y + a1y) + (a2y + a3y);
    float di = dinv[i];
    float2 hv = *(const float2*)(h2s + (size_t)i * 2);
    out[(size_t)i * 2]     = fmaf(di, ax + hv.x, b2[0]);
    out[(size_t)i * 2 + 1] = fmaf(di, ay + hv.y, b2[1]);
}

extern "C" void kernel_launch(void* const* d_in, const int* in_sizes, int n_in,
                              void* d_out, int out_size, void* d_ws, size_t ws_size,
                              hipStream_t stream) {
    const float* x  = (const float*)d_in[0];
    const int*   ei = (const int*)d_in[1];
    const float* W1 = (const float*)d_in[2];
    const float* b1 = (const float*)d_in[3];
    const float* W2 = (const float*)d_in[4];
    const float* b2 = (const float*)d_in[5];
    float* out = (float*)d_out;

    int N = in_sizes[0] / 128;   // 100000
    int E = in_sizes[1] / 2;     // 1600000
    const int* row = ei;
    const int* col = ei + E;

    char* ws = (char*)d_ws;
    size_t off = 0;
    auto alloc = [&](size_t bytes) -> char* {
        char* p = ws + off;
        off = WS_ALIGN(off + bytes);
        return p;
    };
    int*   deg    = (int*)alloc((size_t)N * 4);
    int*   offs   = (int*)alloc((size_t)(N + 1) * 4);
    int*   cursor = (int*)alloc((size_t)N * 4);
    int*   bsums  = (int*)alloc(4096);
    float* dinv   = (float*)alloc((size_t)N * 4);
    int*   adj    = (int*)alloc((size_t)E * 4);
    float* h1s    = (float*)alloc((size_t)N * 64 * 4);
    float* h2s    = (float*)alloc((size_t)N * 2 * 4);

    int nb = (N + 1023) / 1024;
    int npg = (N + 7) / 8;

    hipMemsetAsync(deg, 0, (size_t)N * 4, stream);
    hipLaunchKernelGGL(k_count, dim3((E + 255) / 256), dim3(256), 0, stream, col, deg, E);
    hipLaunchKernelGGL(k_scan_blocks, dim3(nb), dim3(1024), 0, stream, deg, offs + 1, bsums, N);
    hipLaunchKernelGGL(k_scan_sums, dim3(1), dim3(1024), 0, stream, bsums, nb);
    hipLaunchKernelGGL(k_add_offsets, dim3((N + 255) / 256), dim3(256), 0, stream, offs, bsums, N);
    hipLaunchKernelGGL(k_dinv_cursor, dim3((N + 255) / 256), dim3(256), 0, stream, deg, offs, dinv, cursor, N);
    hipLaunchKernelGGL(k_bin, dim3(1024), dim3(256), 0, stream, row, col, cursor, adj, E, npg);
    hipLaunchKernelGGL(k_gemm1, dim3((N + 31) / 32), dim3(256), 0, stream, x, W1, dinv, h1s, N);
    hipLaunchKernelGGL(k_agg1, dim3((N + 3) / 4), dim3(256), 0, stream, h1s, dinv, offs, adj, b1, W2, h2s, N);
    hipLaunchKernelGGL(k_agg2, dim3((N + 255) / 256), dim3(256), 0, stream, h2s, dinv, offs, adj, b2, out, N);
}